// Round 6
// baseline (183.609 us; speedup 1.0000x reference)
//
#include <hip/hip_runtime.h>
#include <hip/hip_bf16.h>

#define BATCH 32
#define DZ    8192
#define LG    576
#define LL    256
#define CH    512

// ---- ws layout (byte offsets) ----
#define OFF_S      0                          // float[2*1024] raw Gram S
#define OFF_BSUM   8192                       // double[32*5] per-block stats
#define OFF_SELSUM 9472                       // double[4*32] per-(v,b) mse sums
#define OFF_DONE   10496                      // unsigned[1] last-block counter
#define OFF_NG     10560                      // float[BATCH*LG]
#define OFF_NL     84288                      // float[BATCH*LL]
#define OFF_ROWNN  117056                     // u64[BATCH*LG]
#define OFF_COLNN  264512                     // u64[BATCH*LL] (contiguous w/ ROWNN)
#define OFF_ABF    330048                     // bf16 bits [BATCH*LG*CH]
#define OFF_BBF    19204416                   // bf16 bits [BATCH*LL*CH]
#define WS_NEED    27593024

typedef __attribute__((ext_vector_type(8))) short bf16x8;
typedef __attribute__((ext_vector_type(4))) float f32x4;

__device__ __forceinline__ unsigned short f2bf(float x) {
  union { __hip_bfloat16 h; unsigned short u; } cv;
  cv.h = __float2bfloat16(x);
  return cv.u;
}

// -------- selection core (compile-time specialized per direction) --------
struct SelSmem {
  unsigned long long keys[LG];
  unsigned int nnm[LG];
  float cxy[2 * LG];
  unsigned int plist[40];
  unsigned int cnt;
  float fred[4];
};

template <int V>
__device__ __forceinline__ void sel_case(
    SelSmem& sm, int b,
    const float* __restrict__ zgf, const float* __restrict__ zlf,
    const float* __restrict__ gg, const float* __restrict__ gl,
    const unsigned long long* __restrict__ rowNN,
    const unsigned long long* __restrict__ colNN,
    double* __restrict__ selsum) {
  constexpr bool GDIR = (V == 0 || V == 2);
  constexpr int L1 = GDIR ? LG : LL;
  constexpr int L2 = GDIR ? LL : LG;
  constexpr int M  = GDIR ? 20 : 4;
  constexpr int NR = (L1 + 255) / 256;
  const float* fin  = GDIR ? zgf + (size_t)b * LG * CH : zlf + (size_t)b * LL * CH;
  const float* fcan = GDIR ? zlf + (size_t)b * LL * CH : zgf + (size_t)b * LG * CH;
  int tid = threadIdx.x, lane = tid & 63, wv = tid >> 6;
  if (tid == 0) sm.cnt = 0;

  if constexpr (V < 2) {
    const unsigned long long* src =
        (V == 0) ? rowNN + (size_t)b * LG : colNN + (size_t)b * LL;
    #pragma unroll
    for (int s = 0; s < NR; ++s) {
      int l = tid + s * 256;
      if (l < L1) {
        unsigned long long p = src[l];
        sm.keys[l] = (p & 0xFFFFFFFF00000000ull) | (unsigned)l;
        sm.nnm[l] = (unsigned)(p & 0xFFFFFFFFu);
      }
    }
  } else {
    const float* gin  = (V == 2) ? gg + (size_t)b * LG * 2 : gl + (size_t)b * LL * 2;
    const float* gcan = (V == 2) ? gl + (size_t)b * LL * 2 : gg + (size_t)b * LG * 2;
    #pragma unroll
    for (int s = 0; s < (2 * L2 + 255) / 256; ++s) {
      int i = tid + s * 256;
      if (i < 2 * L2) sm.cxy[i] = gcan[i];
    }
    __syncthreads();
    float x[NR], y[NR], bd[NR];
    unsigned bi[NR];
    #pragma unroll
    for (int s = 0; s < NR; ++s) {
      int l = tid + s * 256;
      x[s] = (l < L1) ? gin[2 * l] : 0.f;
      y[s] = (l < L1) ? gin[2 * l + 1] : 0.f;
      bd[s] = 3.4e38f; bi[s] = 0;
    }
    const float2* c2 = (const float2*)sm.cxy;
    for (int m2 = 0; m2 < L2; m2 += 8) {
      float2 cc[8];                          // 8 LDS loads in flight
      #pragma unroll
      for (int u = 0; u < 8; ++u) cc[u] = c2[m2 + u];
      #pragma unroll
      for (int u = 0; u < 8; ++u)
        #pragma unroll
        for (int s = 0; s < NR; ++s) {
          float dx = x[s] - cc[u].x, dy = y[s] - cc[u].y;
          float d2 = dx * dx + dy * dy;
          if (d2 < bd[s]) { bd[s] = d2; bi[s] = (unsigned)(m2 + u); }  // first-min
        }
    }
    #pragma unroll
    for (int s = 0; s < NR; ++s) {
      int l = tid + s * 256;
      if (l < L1) {
        sm.keys[l] = ((unsigned long long)__float_as_uint(bd[s]) << 32) | (unsigned)l;
        sm.nnm[l] = bi[s];
      }
    }
  }
  __syncthreads();

  // rank count with 8-wide batched LDS reads
  unsigned long long myk[NR];
  int rk[NR];
  #pragma unroll
  for (int s = 0; s < NR; ++s) {
    int l = tid + s * 256;
    myk[s] = (l < L1) ? sm.keys[l] : ~0ull;
    rk[s] = 0;
  }
  for (int j = 0; j < L1; j += 8) {
    unsigned long long kk[8];
    #pragma unroll
    for (int u = 0; u < 8; ++u) kk[u] = sm.keys[j + u];
    #pragma unroll
    for (int u = 0; u < 8; ++u)
      #pragma unroll
      for (int s = 0; s < NR; ++s) rk[s] += (kk[u] < myk[s]) ? 1 : 0;
  }
  #pragma unroll
  for (int s = 0; s < NR; ++s) {
    int l = tid + s * 256;
    if (l < L1 && rk[s] < M) {
      unsigned slot = atomicAdd(&sm.cnt, 1u);
      sm.plist[2 * slot] = (unsigned)l;
      sm.plist[2 * slot + 1] = sm.nnm[l];
    }
  }
  __syncthreads();

  // MSE: wave-per-pair, fully unrolled float4 gathers
  float part = 0.f;
  #pragma unroll
  for (int rr = 0; rr < M / 4; ++rr) {
    int r = wv + rr * 4;
    const float4* a4 = (const float4*)(fin + (size_t)sm.plist[2 * r] * CH);
    const float4* c4 = (const float4*)(fcan + (size_t)sm.plist[2 * r + 1] * CH);
    float4 xa = a4[lane * 2], xb = a4[lane * 2 + 1];
    float4 ya = c4[lane * 2], yb = c4[lane * 2 + 1];
    float d0 = xa.x - ya.x, d1 = xa.y - ya.y, d2 = xa.z - ya.z, d3 = xa.w - ya.w;
    float d4 = xb.x - yb.x, d5 = xb.y - yb.y, d6 = xb.z - yb.z, d7 = xb.w - yb.w;
    part += d0 * d0 + d1 * d1 + d2 * d2 + d3 * d3 +
            d4 * d4 + d5 * d5 + d6 * d6 + d7 * d7;
  }
  for (int s = 32; s; s >>= 1) part += __shfl_down(part, s);
  if (lane == 0) sm.fred[wv] = part;
  __syncthreads();
  if (tid == 0)
    selsum[V * 32 + b] = (double)(sm.fred[0] + sm.fred[1] + sm.fred[2] + sm.fred[3]);
}

// -------- front: ALL input-only work in ONE dispatch --------
// blocks [0,32): per-feature stats; [32,1088): Gram pairs; [1088,7744): prep;
// [7744,7808): grid-space NN + MSE (V=2,3).
__global__ __launch_bounds__(256) void k_front(
    const float* __restrict__ za, const float* __restrict__ zb,
    const float* __restrict__ zgf, const float* __restrict__ zlf,
    const float* __restrict__ gg, const float* __restrict__ gl,
    double* __restrict__ bsum, float* __restrict__ S,
    unsigned short* __restrict__ Abf, unsigned short* __restrict__ Bbf,
    float* __restrict__ ng, float* __restrict__ nl,
    unsigned long long* __restrict__ nnInit,
    double* __restrict__ selsum, unsigned* __restrict__ done, int do_bf16) {
  __shared__ float sred[4][8];
  __shared__ SelSmem sm;
  int tid = threadIdx.x, lane = tid & 63, wv = tid >> 6;
  int blk = blockIdx.x;

  if (blk < 32) {
    if (blk == 0 && tid == 0) *done = 0u;    // init last-block counter for k_sel
    int i = blk * 256 + tid;                 // feature 0..8191
    float sa = 0.f, qa = 0.f, sb = 0.f, qb = 0.f, si = 0.f;
    #pragma unroll 8
    for (int b = 0; b < BATCH; ++b) {
      float va = za[(size_t)b * DZ + i];
      float vb = zb[(size_t)b * DZ + i];
      sa += va; qa += va * va;
      sb += vb; qb += vb * vb;
      float d = va - vb; si += d * d;
    }
    float ssa = qa - sa * sa * (1.f / 32.f); // centered SS = 31*var
    float ssb = qb - sb * sb * (1.f / 32.f);
    float v0 = si;
    float v1 = fmaxf(0.f, 1.f - sqrtf(ssa * (1.f / 31.f) + 1e-4f));
    float v2 = fmaxf(0.f, 1.f - sqrtf(ssb * (1.f / 31.f) + 1e-4f));
    float v3 = ssa * ssa, v4 = ssb * ssb;
    for (int off = 32; off; off >>= 1) {
      v0 += __shfl_down(v0, off); v1 += __shfl_down(v1, off);
      v2 += __shfl_down(v2, off); v3 += __shfl_down(v3, off);
      v4 += __shfl_down(v4, off);
    }
    if (lane == 0) {
      sred[wv][0] = v0; sred[wv][1] = v1; sred[wv][2] = v2;
      sred[wv][3] = v3; sred[wv][4] = v4;
    }
    __syncthreads();
    if (tid < 5)
      bsum[blk * 5 + tid] =
          (double)(sred[0][tid] + sred[1][tid] + sred[2][tid] + sred[3][tid]);
  } else if (blk < 1088) {
    int e = blk - 32;                        // 0..1055
    int zi = e >= 528; if (zi) e -= 528;
    const float* z = zi ? zb : za;
    float* Sz = S + zi * 1024;
    int p = 0, rem = e;
    while (rem >= 32 - p) { rem -= 32 - p; ++p; }
    int q = p + rem;
    const float4* zp = (const float4*)(z + (size_t)p * DZ);
    const float4* zq = (const float4*)(z + (size_t)q * DZ);
    float s = 0.f;
    #pragma unroll
    for (int ii = 0; ii < 8; ++ii) {
      int i = tid + ii * 256;
      float4 a = zp[i], b = zq[i];
      s += a.x * b.x + a.y * b.y + a.z * b.z + a.w * b.w;
    }
    for (int off = 32; off; off >>= 1) s += __shfl_down(s, off);
    if (lane == 0) sred[wv][0] = s;
    __syncthreads();
    if (tid == 0) {
      float r = sred[0][0] + sred[1][0] + sred[2][0] + sred[3][0];
      Sz[p * 32 + q] = r;
      if (p != q) Sz[q * 32 + p] = r;
    }
  } else if (blk < 7744) {
    int row = (blk - 1088) * 4 + wv;         // 0..26623
    if (lane == 0) nnInit[row] = ~0ull;      // rowNN/colNN contiguous, 1:1 rows
    const float* src; unsigned short* dst; float* nrm;
    if (row < BATCH * LG) {
      src = zgf + (size_t)row * CH; dst = Abf + (size_t)row * CH; nrm = ng + row;
    } else {
      int rr = row - BATCH * LG;
      src = zlf + (size_t)rr * CH; dst = Bbf + (size_t)rr * CH; nrm = nl + rr;
    }
    const float4* s4 = (const float4*)src;
    float4 v0 = s4[lane * 2], v1 = s4[lane * 2 + 1];
    float ss = v0.x * v0.x + v0.y * v0.y + v0.z * v0.z + v0.w * v0.w +
               v1.x * v1.x + v1.y * v1.y + v1.z * v1.z + v1.w * v1.w;
    if (do_bf16) {
      union { unsigned short h[8]; uint4 u; } pk;
      pk.h[0] = f2bf(v0.x); pk.h[1] = f2bf(v0.y); pk.h[2] = f2bf(v0.z); pk.h[3] = f2bf(v0.w);
      pk.h[4] = f2bf(v1.x); pk.h[5] = f2bf(v1.y); pk.h[6] = f2bf(v1.z); pk.h[7] = f2bf(v1.w);
      *(uint4*)(dst + lane * 8) = pk.u;
    }
    for (int off = 32; off; off >>= 1) ss += __shfl_down(ss, off);
    if (lane == 0) *nrm = ss;
  } else {
    int e = blk - 7744;                      // grid-space NN+MSE, V=2 (g) / 3 (l)
    int b = e & 31;
    if (e >> 5)
      sel_case<3>(sm, b, zgf, zlf, gg, gl, nnInit, nnInit, selsum);
    else
      sel_case<2>(sm, b, zgf, zlf, gg, gl, nnInit, nnInit, selsum);
  }
}

// -------- feature-space cdist via bf16 MFMA + fused NN argmin --------
__global__ __launch_bounds__(256) void k_feat_mfma(
    const unsigned short* __restrict__ Abf, const unsigned short* __restrict__ Bbf,
    const float* __restrict__ ng, const float* __restrict__ nl,
    unsigned long long* __restrict__ rowNN, unsigned long long* __restrict__ colNN) {
  const int b = blockIdx.z;
  const int row0 = blockIdx.x * 64;
  const int col0 = blockIdx.y * 64;
  const int tid = threadIdx.x;
  const int wave = tid >> 6, lane = tid & 63;
  const int m16 = lane & 15, quad = lane >> 4;
  const int wm = wave >> 1, wn = wave & 1;

  __shared__ unsigned short As[64][72];
  __shared__ unsigned short Bs[64][72];

  const unsigned short* Ag = Abf + ((size_t)(b * LG + row0)) * CH;
  const unsigned short* Bg = Bbf + ((size_t)(b * LL + col0)) * CH;

  const int sr = tid >> 2;
  const int sq = tid & 3;

  f32x4 acc[2][2] = {};

  for (int k0 = 0; k0 < CH; k0 += 64) {
    uint4 a0 = *(const uint4*)(Ag + (size_t)sr * CH + k0 + sq * 16);
    uint4 a1 = *(const uint4*)(Ag + (size_t)sr * CH + k0 + sq * 16 + 8);
    uint4 b0 = *(const uint4*)(Bg + (size_t)sr * CH + k0 + sq * 16);
    uint4 b1 = *(const uint4*)(Bg + (size_t)sr * CH + k0 + sq * 16 + 8);
    __syncthreads();
    *(uint4*)&As[sr][sq * 16] = a0; *(uint4*)&As[sr][sq * 16 + 8] = a1;
    *(uint4*)&Bs[sr][sq * 16] = b0; *(uint4*)&Bs[sr][sq * 16 + 8] = b1;
    __syncthreads();
    #pragma unroll
    for (int kk = 0; kk < 64; kk += 32) {
      bf16x8 af0 = *(const bf16x8*)&As[wm * 32 + m16][kk + quad * 8];
      bf16x8 af1 = *(const bf16x8*)&As[wm * 32 + 16 + m16][kk + quad * 8];
      bf16x8 bf0 = *(const bf16x8*)&Bs[wn * 32 + m16][kk + quad * 8];
      bf16x8 bf1 = *(const bf16x8*)&Bs[wn * 32 + 16 + m16][kk + quad * 8];
      acc[0][0] = __builtin_amdgcn_mfma_f32_16x16x32_bf16(af0, bf0, acc[0][0], 0, 0, 0);
      acc[0][1] = __builtin_amdgcn_mfma_f32_16x16x32_bf16(af0, bf1, acc[0][1], 0, 0, 0);
      acc[1][0] = __builtin_amdgcn_mfma_f32_16x16x32_bf16(af1, bf0, acc[1][0], 0, 0, 0);
      acc[1][1] = __builtin_amdgcn_mfma_f32_16x16x32_bf16(af1, bf1, acc[1][1], 0, 0, 0);
    }
  }

  float na[2][4], nb[2];
  #pragma unroll
  for (int i = 0; i < 2; ++i)
    #pragma unroll
    for (int r = 0; r < 4; ++r)
      na[i][r] = ng[b * LG + row0 + wm * 32 + i * 16 + quad * 4 + r];
  #pragma unroll
  for (int j = 0; j < 2; ++j)
    nb[j] = nl[b * LL + col0 + wn * 32 + j * 16 + m16];

  #pragma unroll
  for (int i = 0; i < 2; ++i) {
    #pragma unroll
    for (int r = 0; r < 4; ++r) {
      float d0 = fmaxf(na[i][r] + nb[0] - 2.f * acc[i][0][r], 0.f);
      float d1 = fmaxf(na[i][r] + nb[1] - 2.f * acc[i][1][r], 0.f);
      unsigned c0 = (unsigned)(col0 + wn * 32 + m16);
      unsigned long long p0 = (((unsigned long long)__float_as_uint(d0)) << 32) | c0;
      unsigned long long p1 = (((unsigned long long)__float_as_uint(d1)) << 32) | (c0 + 16);
      unsigned long long p = p0 < p1 ? p0 : p1;
      #pragma unroll
      for (int s = 1; s < 16; s <<= 1) {
        unsigned long long q = __shfl_xor(p, s);
        p = q < p ? q : p;
      }
      if (m16 == 0)
        atomicMin(&rowNN[(size_t)b * LG + row0 + wm * 32 + i * 16 + quad * 4 + r], p);
    }
  }
  #pragma unroll
  for (int j = 0; j < 2; ++j) {
    unsigned long long p = ~0ull;
    #pragma unroll
    for (int i = 0; i < 2; ++i) {
      #pragma unroll
      for (int r = 0; r < 4; ++r) {
        float d = fmaxf(na[i][r] + nb[j] - 2.f * acc[i][j][r], 0.f);
        unsigned rg = (unsigned)(row0 + wm * 32 + i * 16 + quad * 4 + r);
        unsigned long long pr = (((unsigned long long)__float_as_uint(d)) << 32) | rg;
        p = pr < p ? pr : p;
      }
    }
    unsigned long long q = __shfl_xor(p, 16); p = q < p ? q : p;
    q = __shfl_xor(p, 32); p = q < p ? q : p;
    if (quad == 0)
      atomicMin(&colNN[(size_t)b * LL + col0 + wn * 32 + j * 16 + m16], p);
  }
}

// -------- FALLBACK (small ws): fp32 VALU cdist + NN --------
__global__ __launch_bounds__(256) void k_feat_nn(
    const float* __restrict__ zgf, const float* __restrict__ zlf,
    const float* __restrict__ ng, const float* __restrict__ nl,
    unsigned long long* __restrict__ rowNN, unsigned long long* __restrict__ colNN) {
  const int b = blockIdx.z;
  const int row0 = blockIdx.x * 64;
  const int col0 = blockIdx.y * 128;
  const int tid = threadIdx.x;
  const int tx = tid & 15, ty = tid >> 4;
  __shared__ float As[64][20];
  __shared__ float Bs[128][20];
  __shared__ float Ds[64][130];
  const float* Ag = zgf + ((size_t)b * LG + row0) * CH;
  const float* Bg = zlf + ((size_t)b * LL + col0) * CH;
  float acc[4][8];
  #pragma unroll
  for (int i = 0; i < 4; ++i)
    #pragma unroll
    for (int j = 0; j < 8; ++j) acc[i][j] = 0.f;
  const int ar = tid >> 2;
  const int ak = (tid & 3) * 4;
  for (int k0 = 0; k0 < CH; k0 += 16) {
    float4 av  = *(const float4*)(Ag + (size_t)ar * CH + k0 + ak);
    float4 bv0 = *(const float4*)(Bg + (size_t)ar * CH + k0 + ak);
    float4 bv1 = *(const float4*)(Bg + (size_t)(ar + 64) * CH + k0 + ak);
    __syncthreads();
    *(float4*)&As[ar][ak] = av;
    *(float4*)&Bs[ar][ak] = bv0;
    *(float4*)&Bs[ar + 64][ak] = bv1;
    __syncthreads();
    #pragma unroll
    for (int k = 0; k < 16; ++k) {
      float a0 = As[ty][k], a1 = As[ty + 16][k], a2 = As[ty + 32][k], a3 = As[ty + 48][k];
      float bv[8];
      #pragma unroll
      for (int j = 0; j < 8; ++j) bv[j] = Bs[tx + 16 * j][k];
      #pragma unroll
      for (int j = 0; j < 8; ++j) {
        acc[0][j] += a0 * bv[j]; acc[1][j] += a1 * bv[j];
        acc[2][j] += a2 * bv[j]; acc[3][j] += a3 * bv[j];
      }
    }
  }
  float ngr[4], nlc[8];
  #pragma unroll
  for (int i = 0; i < 4; ++i) ngr[i] = ng[b * LG + row0 + ty + 16 * i];
  #pragma unroll
  for (int j = 0; j < 8; ++j) nlc[j] = nl[b * LL + col0 + tx + 16 * j];
  #pragma unroll
  for (int i = 0; i < 4; ++i)
    #pragma unroll
    for (int j = 0; j < 8; ++j)
      Ds[ty + 16 * i][tx + 16 * j] = fmaxf(ngr[i] + nlc[j] - 2.f * acc[i][j], 0.f);
  __syncthreads();
  if (tid < 64) {
    unsigned long long best = ~0ull;
    for (int c = 0; c < 128; ++c) {
      unsigned long long p =
          ((unsigned long long)__float_as_uint(Ds[tid][c]) << 32) | (unsigned)(col0 + c);
      best = p < best ? p : best;
    }
    atomicMin(&rowNN[(size_t)b * LG + row0 + tid], best);
  } else if (tid < 192) {
    int c = tid - 64;
    unsigned long long best = ~0ull;
    for (int r = 0; r < 64; ++r) {
      unsigned long long p =
          ((unsigned long long)__float_as_uint(Ds[r][c]) << 32) | (unsigned)(row0 + r);
      best = p < best ? p : best;
    }
    atomicMin(&colNN[(size_t)b * LL + col0 + c], best);
  }
}

// -------- feature-dir selection + fused final (last block combines) --------
__global__ __launch_bounds__(256) void k_sel(
    const float* __restrict__ zgf, const float* __restrict__ zlf,
    const float* __restrict__ gg, const float* __restrict__ gl,
    const unsigned long long* __restrict__ rowNN,
    const unsigned long long* __restrict__ colNN,
    double* __restrict__ selsum, const double* __restrict__ bsum,
    const float* __restrict__ S, unsigned* __restrict__ done,
    float* __restrict__ out) {
  __shared__ SelSmem sm;
  int b = blockIdx.x;
  if (blockIdx.y == 0)
    sel_case<0>(sm, b, zgf, zlf, gg, gl, rowNN, colNN, selsum);
  else
    sel_case<1>(sm, b, zgf, zlf, gg, gl, rowNN, colNN, selsum);

  // ---- last of 64 blocks performs the final combine ----
  __shared__ unsigned isLast;
  __shared__ float t[2][32];
  __shared__ double sacc[5];
  __shared__ double smf[4];
  __shared__ double totred[2];
  int tid = threadIdx.x, lane = tid & 63, wv = tid >> 6;
  if (tid == 0) {
    __threadfence();
    unsigned old = __hip_atomic_fetch_add(done, 1u, __ATOMIC_ACQ_REL,
                                          __HIP_MEMORY_SCOPE_AGENT);
    isLast = (old == 63u) ? 1u : 0u;
  }
  __syncthreads();
  if (isLast) {
    __threadfence();
    if (tid < 64) {
      int zi = tid >> 5, p = tid & 31;
      float tp = 0.f;
      for (int bb = 0; bb < 32; ++bb) tp += S[zi * 1024 + p * 32 + bb];
      t[zi][p] = tp * (1.f / 32.f);
    } else if (tid < 69) {
      int k = tid - 64;
      double s = 0.0;
      for (int blk = 0; blk < 32; ++blk) s += bsum[blk * 5 + k];
      sacc[k] = s;
    } else if (tid >= 72 && tid < 76) {
      int v = tid - 72;
      double s = 0.0;
      for (int bb = 0; bb < 32; ++bb) s += selsum[v * 32 + bb];
      smf[v] = s;
    }
    __syncthreads();
    if (wv < 2) {
      int zi = wv;
      float u = 0.f;
      for (int bb = 0; bb < 32; ++bb) u += t[zi][bb];
      u *= (1.f / 32.f);
      double s = 0.0;
      for (int e = lane; e < 1024; e += 64) {
        int p = e >> 5, q = e & 31;
        float G = S[zi * 1024 + e] - t[zi][p] - t[zi][q] + u;
        s += (double)G * (double)G;
      }
      for (int off = 32; off; off >>= 1) s += __shfl_down(s, off);
      if (lane == 0) totred[zi] = s;
    }
    __syncthreads();
    if (tid == 0) {
      double inv_g = sacc[0] / (32.0 * 8192.0);
      double v = 0.5 * (sacc[1] + sacc[2]) / 8192.0;
      double c = (totred[0] - sacc[3] + totred[1] - sacc[4]) / (961.0 * 8192.0);
      double gloss = 25.0 * inv_g + 25.0 * v + c;
      double mfg = smf[0] / (32.0 * 20.0 * 512.0);
      double mfl = smf[1] / (32.0 * 4.0 * 512.0);
      double mgg = smf[2] / (32.0 * 20.0 * 512.0);
      double mgl = smf[3] / (32.0 * 4.0 * 512.0);
      double lloss = 25.0 * (0.5 * (mfg + mfl) + 0.5 * (mgg + mgl));
      out[0] = (float)(0.25 * gloss + 0.75 * lloss);
    }
  }
}

extern "C" void kernel_launch(void* const* d_in, const int* in_sizes, int n_in,
                              void* d_out, int out_size, void* d_ws, size_t ws_size,
                              hipStream_t stream) {
  const float* zg  = (const float*)d_in[0];
  const float* zl  = (const float*)d_in[1];
  const float* zgf = (const float*)d_in[2];
  const float* zlf = (const float*)d_in[3];
  const float* gg  = (const float*)d_in[4];
  const float* glo = (const float*)d_in[5];

  char* ws = (char*)d_ws;
  float* S       = (float*)(ws + OFF_S);
  double* bsum   = (double*)(ws + OFF_BSUM);
  double* selsum = (double*)(ws + OFF_SELSUM);
  unsigned* done = (unsigned*)(ws + OFF_DONE);
  float* ng = (float*)(ws + OFF_NG);
  float* nl = (float*)(ws + OFF_NL);
  unsigned long long* rowNN = (unsigned long long*)(ws + OFF_ROWNN);
  unsigned long long* colNN = (unsigned long long*)(ws + OFF_COLNN);
  unsigned short* Abf = (unsigned short*)(ws + OFF_ABF);
  unsigned short* Bbf = (unsigned short*)(ws + OFF_BBF);

  int do_bf16 = (ws_size >= WS_NEED) ? 1 : 0;

  k_front<<<7808, 256, 0, stream>>>(zg, zl, zgf, zlf, gg, glo, bsum, S,
                                    Abf, Bbf, ng, nl, rowNN, selsum, done, do_bf16);
  if (do_bf16) {
    k_feat_mfma<<<dim3(LG / 64, LL / 64, BATCH), 256, 0, stream>>>(
        Abf, Bbf, ng, nl, rowNN, colNN);
  } else {
    k_feat_nn<<<dim3(LG / 64, LL / 128, BATCH), 256, 0, stream>>>(
        zgf, zlf, ng, nl, rowNN, colNN);
  }
  k_sel<<<dim3(BATCH, 2), 256, 0, stream>>>(zgf, zlf, gg, glo, rowNN, colNN,
                                            selsum, bsum, S, done, (float*)d_out);
}

// Round 7
// 171.335 us; speedup vs baseline: 1.0716x; 1.0716x over previous
//
#include <hip/hip_runtime.h>
#include <hip/hip_bf16.h>

#define BATCH 32
#define DZ    8192
#define LG    576
#define LL    256
#define CH    512

// ---- ws layout (byte offsets) ----
#define OFF_S      0                          // float[2*1024] raw Gram S
#define OFF_BSUM   8192                       // double[32*5] per-block stats
#define OFF_SELSUM 9472                       // double[4*32] per-(v,b) mse sums
#define OFF_DONE   10496                      // unsigned[1] last-block counter
#define OFF_NG     10560                      // float[BATCH*LG]
#define OFF_NL     84288                      // float[BATCH*LL]
#define OFF_ROWNN  117056                     // u64[BATCH*LG]
#define OFF_COLNN  264512                     // u64[BATCH*LL] (contiguous w/ ROWNN)
#define OFF_ABF    330048                     // bf16 bits [BATCH*LG*CH]
#define OFF_BBF    19204416                   // bf16 bits [BATCH*LL*CH]
#define WS_NEED    27593024

typedef __attribute__((ext_vector_type(8))) short bf16x8;
typedef __attribute__((ext_vector_type(4))) float f32x4;

__device__ __forceinline__ unsigned short f2bf(float x) {
  union { __hip_bfloat16 h; unsigned short u; } cv;
  cv.h = __float2bfloat16(x);
  return cv.u;
}

// -------- selection core (compile-time specialized per direction) --------
struct SelSmem {
  unsigned long long keys[LG];
  unsigned int nnm[LG];
  float cxy[2 * LG];
  unsigned int plist[40];
  unsigned int cnt;
  float fred[4];
};

template <int V>
__device__ __forceinline__ void sel_case(
    SelSmem& sm, int b,
    const float* __restrict__ zgf, const float* __restrict__ zlf,
    const float* __restrict__ gg, const float* __restrict__ gl,
    const unsigned long long* __restrict__ rowNN,
    const unsigned long long* __restrict__ colNN,
    double* __restrict__ selsum) {
  constexpr bool GDIR = (V == 0 || V == 2);
  constexpr int L1 = GDIR ? LG : LL;
  constexpr int L2 = GDIR ? LL : LG;
  constexpr int M  = GDIR ? 20 : 4;
  constexpr int NR = (L1 + 255) / 256;
  const float* fin  = GDIR ? zgf + (size_t)b * LG * CH : zlf + (size_t)b * LL * CH;
  const float* fcan = GDIR ? zlf + (size_t)b * LL * CH : zgf + (size_t)b * LG * CH;
  int tid = threadIdx.x, lane = tid & 63, wv = tid >> 6;
  if (tid == 0) sm.cnt = 0;

  if constexpr (V < 2) {
    const unsigned long long* src =
        (V == 0) ? rowNN + (size_t)b * LG : colNN + (size_t)b * LL;
    #pragma unroll
    for (int s = 0; s < NR; ++s) {
      int l = tid + s * 256;
      if (l < L1) {
        unsigned long long p = src[l];
        sm.keys[l] = (p & 0xFFFFFFFF00000000ull) | (unsigned)l;
        sm.nnm[l] = (unsigned)(p & 0xFFFFFFFFu);
      }
    }
  } else {
    const float* gin  = (V == 2) ? gg + (size_t)b * LG * 2 : gl + (size_t)b * LL * 2;
    const float* gcan = (V == 2) ? gl + (size_t)b * LL * 2 : gg + (size_t)b * LG * 2;
    #pragma unroll
    for (int s = 0; s < (2 * L2 + 255) / 256; ++s) {
      int i = tid + s * 256;
      if (i < 2 * L2) sm.cxy[i] = gcan[i];
    }
    __syncthreads();
    float x[NR], y[NR], bd[NR];
    unsigned bi[NR];
    #pragma unroll
    for (int s = 0; s < NR; ++s) {
      int l = tid + s * 256;
      x[s] = (l < L1) ? gin[2 * l] : 0.f;
      y[s] = (l < L1) ? gin[2 * l + 1] : 0.f;
      bd[s] = 3.4e38f; bi[s] = 0;
    }
    const float2* c2 = (const float2*)sm.cxy;
    for (int m2 = 0; m2 < L2; m2 += 8) {
      float2 cc[8];                          // 8 LDS loads in flight
      #pragma unroll
      for (int u = 0; u < 8; ++u) cc[u] = c2[m2 + u];
      #pragma unroll
      for (int u = 0; u < 8; ++u)
        #pragma unroll
        for (int s = 0; s < NR; ++s) {
          float dx = x[s] - cc[u].x, dy = y[s] - cc[u].y;
          float d2 = dx * dx + dy * dy;
          if (d2 < bd[s]) { bd[s] = d2; bi[s] = (unsigned)(m2 + u); }  // first-min
        }
    }
    #pragma unroll
    for (int s = 0; s < NR; ++s) {
      int l = tid + s * 256;
      if (l < L1) {
        sm.keys[l] = ((unsigned long long)__float_as_uint(bd[s]) << 32) | (unsigned)l;
        sm.nnm[l] = bi[s];
      }
    }
  }
  __syncthreads();

  // rank count with 8-wide batched LDS reads
  unsigned long long myk[NR];
  int rk[NR];
  #pragma unroll
  for (int s = 0; s < NR; ++s) {
    int l = tid + s * 256;
    myk[s] = (l < L1) ? sm.keys[l] : ~0ull;
    rk[s] = 0;
  }
  for (int j = 0; j < L1; j += 8) {
    unsigned long long kk[8];
    #pragma unroll
    for (int u = 0; u < 8; ++u) kk[u] = sm.keys[j + u];
    #pragma unroll
    for (int u = 0; u < 8; ++u)
      #pragma unroll
      for (int s = 0; s < NR; ++s) rk[s] += (kk[u] < myk[s]) ? 1 : 0;
  }
  #pragma unroll
  for (int s = 0; s < NR; ++s) {
    int l = tid + s * 256;
    if (l < L1 && rk[s] < M) {
      unsigned slot = atomicAdd(&sm.cnt, 1u);
      sm.plist[2 * slot] = (unsigned)l;
      sm.plist[2 * slot + 1] = sm.nnm[l];
    }
  }
  __syncthreads();

  // MSE: wave-per-pair, fully unrolled float4 gathers
  float part = 0.f;
  #pragma unroll
  for (int rr = 0; rr < M / 4; ++rr) {
    int r = wv + rr * 4;
    const float4* a4 = (const float4*)(fin + (size_t)sm.plist[2 * r] * CH);
    const float4* c4 = (const float4*)(fcan + (size_t)sm.plist[2 * r + 1] * CH);
    float4 xa = a4[lane * 2], xb = a4[lane * 2 + 1];
    float4 ya = c4[lane * 2], yb = c4[lane * 2 + 1];
    float d0 = xa.x - ya.x, d1 = xa.y - ya.y, d2 = xa.z - ya.z, d3 = xa.w - ya.w;
    float d4 = xb.x - yb.x, d5 = xb.y - yb.y, d6 = xb.z - yb.z, d7 = xb.w - yb.w;
    part += d0 * d0 + d1 * d1 + d2 * d2 + d3 * d3 +
            d4 * d4 + d5 * d5 + d6 * d6 + d7 * d7;
  }
  for (int s = 32; s; s >>= 1) part += __shfl_down(part, s);
  if (lane == 0) sm.fred[wv] = part;
  __syncthreads();
  if (tid == 0)
    selsum[V * 32 + b] = (double)(sm.fred[0] + sm.fred[1] + sm.fred[2] + sm.fred[3]);
}

// -------- front: ALL input-only work in ONE dispatch --------
// Long-latency blocks FIRST so they overlap the BW-bound bulk:
// [0,64): grid-space NN + MSE (V=2,3); [64,96): per-feature stats;
// [96,1152): Gram pairs; [1152,7808): prep (bf16 cvt + norms + NN init).
__global__ __launch_bounds__(256) void k_front(
    const float* __restrict__ za, const float* __restrict__ zb,
    const float* __restrict__ zgf, const float* __restrict__ zlf,
    const float* __restrict__ gg, const float* __restrict__ gl,
    double* __restrict__ bsum, float* __restrict__ S,
    unsigned short* __restrict__ Abf, unsigned short* __restrict__ Bbf,
    float* __restrict__ ng, float* __restrict__ nl,
    unsigned long long* __restrict__ nnInit,
    double* __restrict__ selsum, unsigned* __restrict__ done, int do_bf16) {
  __shared__ float sred[4][8];
  __shared__ SelSmem sm;
  int tid = threadIdx.x, lane = tid & 63, wv = tid >> 6;
  int blk = blockIdx.x;

  if (blk < 64) {
    if (blk == 0 && tid == 0) *done = 0u;    // init last-block counter for k_sel
    int b = blk & 31;
    if (blk >> 5)
      sel_case<3>(sm, b, zgf, zlf, gg, gl, nnInit, nnInit, selsum);
    else
      sel_case<2>(sm, b, zgf, zlf, gg, gl, nnInit, nnInit, selsum);
  } else if (blk < 96) {
    int sblk = blk - 64;
    int i = sblk * 256 + tid;                // feature 0..8191
    float sa = 0.f, qa = 0.f, sb = 0.f, qb = 0.f, si = 0.f;
    #pragma unroll 8
    for (int b = 0; b < BATCH; ++b) {
      float va = za[(size_t)b * DZ + i];
      float vb = zb[(size_t)b * DZ + i];
      sa += va; qa += va * va;
      sb += vb; qb += vb * vb;
      float d = va - vb; si += d * d;
    }
    float ssa = qa - sa * sa * (1.f / 32.f); // centered SS = 31*var
    float ssb = qb - sb * sb * (1.f / 32.f);
    float v0 = si;
    float v1 = fmaxf(0.f, 1.f - sqrtf(ssa * (1.f / 31.f) + 1e-4f));
    float v2 = fmaxf(0.f, 1.f - sqrtf(ssb * (1.f / 31.f) + 1e-4f));
    float v3 = ssa * ssa, v4 = ssb * ssb;
    for (int off = 32; off; off >>= 1) {
      v0 += __shfl_down(v0, off); v1 += __shfl_down(v1, off);
      v2 += __shfl_down(v2, off); v3 += __shfl_down(v3, off);
      v4 += __shfl_down(v4, off);
    }
    if (lane == 0) {
      sred[wv][0] = v0; sred[wv][1] = v1; sred[wv][2] = v2;
      sred[wv][3] = v3; sred[wv][4] = v4;
    }
    __syncthreads();
    if (tid < 5)
      bsum[sblk * 5 + tid] =
          (double)(sred[0][tid] + sred[1][tid] + sred[2][tid] + sred[3][tid]);
  } else if (blk < 1152) {
    int e = blk - 96;                        // 0..1055
    int zi = e >= 528; if (zi) e -= 528;
    const float* z = zi ? zb : za;
    float* Sz = S + zi * 1024;
    int p = 0, rem = e;
    while (rem >= 32 - p) { rem -= 32 - p; ++p; }
    int q = p + rem;
    const float4* zp = (const float4*)(z + (size_t)p * DZ);
    const float4* zq = (const float4*)(z + (size_t)q * DZ);
    float s = 0.f;
    #pragma unroll
    for (int ii = 0; ii < 8; ++ii) {
      int i = tid + ii * 256;
      float4 a = zp[i], b = zq[i];
      s += a.x * b.x + a.y * b.y + a.z * b.z + a.w * b.w;
    }
    for (int off = 32; off; off >>= 1) s += __shfl_down(s, off);
    if (lane == 0) sred[wv][0] = s;
    __syncthreads();
    if (tid == 0) {
      float r = sred[0][0] + sred[1][0] + sred[2][0] + sred[3][0];
      Sz[p * 32 + q] = r;
      if (p != q) Sz[q * 32 + p] = r;
    }
  } else {
    int row = (blk - 1152) * 4 + wv;         // 0..26623
    if (lane == 0) nnInit[row] = ~0ull;      // rowNN/colNN contiguous, 1:1 rows
    const float* src; unsigned short* dst; float* nrm;
    if (row < BATCH * LG) {
      src = zgf + (size_t)row * CH; dst = Abf + (size_t)row * CH; nrm = ng + row;
    } else {
      int rr = row - BATCH * LG;
      src = zlf + (size_t)rr * CH; dst = Bbf + (size_t)rr * CH; nrm = nl + rr;
    }
    const float4* s4 = (const float4*)src;
    float4 v0 = s4[lane * 2], v1 = s4[lane * 2 + 1];
    float ss = v0.x * v0.x + v0.y * v0.y + v0.z * v0.z + v0.w * v0.w +
               v1.x * v1.x + v1.y * v1.y + v1.z * v1.z + v1.w * v1.w;
    if (do_bf16) {
      union { unsigned short h[8]; uint4 u; } pk;
      pk.h[0] = f2bf(v0.x); pk.h[1] = f2bf(v0.y); pk.h[2] = f2bf(v0.z); pk.h[3] = f2bf(v0.w);
      pk.h[4] = f2bf(v1.x); pk.h[5] = f2bf(v1.y); pk.h[6] = f2bf(v1.z); pk.h[7] = f2bf(v1.w);
      *(uint4*)(dst + lane * 8) = pk.u;
    }
    for (int off = 32; off; off >>= 1) ss += __shfl_down(ss, off);
    if (lane == 0) *nrm = ss;
  }
}

// -------- feature-space cdist via bf16 MFMA + fused NN argmin --------
__global__ __launch_bounds__(256) void k_feat_mfma(
    const unsigned short* __restrict__ Abf, const unsigned short* __restrict__ Bbf,
    const float* __restrict__ ng, const float* __restrict__ nl,
    unsigned long long* __restrict__ rowNN, unsigned long long* __restrict__ colNN) {
  const int b = blockIdx.z;
  const int row0 = blockIdx.x * 64;
  const int col0 = blockIdx.y * 64;
  const int tid = threadIdx.x;
  const int wave = tid >> 6, lane = tid & 63;
  const int m16 = lane & 15, quad = lane >> 4;
  const int wm = wave >> 1, wn = wave & 1;

  __shared__ unsigned short As[64][72];
  __shared__ unsigned short Bs[64][72];

  const unsigned short* Ag = Abf + ((size_t)(b * LG + row0)) * CH;
  const unsigned short* Bg = Bbf + ((size_t)(b * LL + col0)) * CH;

  const int sr = tid >> 2;
  const int sq = tid & 3;

  f32x4 acc[2][2] = {};

  for (int k0 = 0; k0 < CH; k0 += 64) {
    uint4 a0 = *(const uint4*)(Ag + (size_t)sr * CH + k0 + sq * 16);
    uint4 a1 = *(const uint4*)(Ag + (size_t)sr * CH + k0 + sq * 16 + 8);
    uint4 b0 = *(const uint4*)(Bg + (size_t)sr * CH + k0 + sq * 16);
    uint4 b1 = *(const uint4*)(Bg + (size_t)sr * CH + k0 + sq * 16 + 8);
    __syncthreads();
    *(uint4*)&As[sr][sq * 16] = a0; *(uint4*)&As[sr][sq * 16 + 8] = a1;
    *(uint4*)&Bs[sr][sq * 16] = b0; *(uint4*)&Bs[sr][sq * 16 + 8] = b1;
    __syncthreads();
    #pragma unroll
    for (int kk = 0; kk < 64; kk += 32) {
      bf16x8 af0 = *(const bf16x8*)&As[wm * 32 + m16][kk + quad * 8];
      bf16x8 af1 = *(const bf16x8*)&As[wm * 32 + 16 + m16][kk + quad * 8];
      bf16x8 bf0 = *(const bf16x8*)&Bs[wn * 32 + m16][kk + quad * 8];
      bf16x8 bf1 = *(const bf16x8*)&Bs[wn * 32 + 16 + m16][kk + quad * 8];
      acc[0][0] = __builtin_amdgcn_mfma_f32_16x16x32_bf16(af0, bf0, acc[0][0], 0, 0, 0);
      acc[0][1] = __builtin_amdgcn_mfma_f32_16x16x32_bf16(af0, bf1, acc[0][1], 0, 0, 0);
      acc[1][0] = __builtin_amdgcn_mfma_f32_16x16x32_bf16(af1, bf0, acc[1][0], 0, 0, 0);
      acc[1][1] = __builtin_amdgcn_mfma_f32_16x16x32_bf16(af1, bf1, acc[1][1], 0, 0, 0);
    }
  }

  float na[2][4], nb[2];
  #pragma unroll
  for (int i = 0; i < 2; ++i)
    #pragma unroll
    for (int r = 0; r < 4; ++r)
      na[i][r] = ng[b * LG + row0 + wm * 32 + i * 16 + quad * 4 + r];
  #pragma unroll
  for (int j = 0; j < 2; ++j)
    nb[j] = nl[b * LL + col0 + wn * 32 + j * 16 + m16];

  #pragma unroll
  for (int i = 0; i < 2; ++i) {
    #pragma unroll
    for (int r = 0; r < 4; ++r) {
      float d0 = fmaxf(na[i][r] + nb[0] - 2.f * acc[i][0][r], 0.f);
      float d1 = fmaxf(na[i][r] + nb[1] - 2.f * acc[i][1][r], 0.f);
      unsigned c0 = (unsigned)(col0 + wn * 32 + m16);
      unsigned long long p0 = (((unsigned long long)__float_as_uint(d0)) << 32) | c0;
      unsigned long long p1 = (((unsigned long long)__float_as_uint(d1)) << 32) | (c0 + 16);
      unsigned long long p = p0 < p1 ? p0 : p1;
      #pragma unroll
      for (int s = 1; s < 16; s <<= 1) {
        unsigned long long q = __shfl_xor(p, s);
        p = q < p ? q : p;
      }
      if (m16 == 0)
        atomicMin(&rowNN[(size_t)b * LG + row0 + wm * 32 + i * 16 + quad * 4 + r], p);
    }
  }
  #pragma unroll
  for (int j = 0; j < 2; ++j) {
    unsigned long long p = ~0ull;
    #pragma unroll
    for (int i = 0; i < 2; ++i) {
      #pragma unroll
      for (int r = 0; r < 4; ++r) {
        float d = fmaxf(na[i][r] + nb[j] - 2.f * acc[i][j][r], 0.f);
        unsigned rg = (unsigned)(row0 + wm * 32 + i * 16 + quad * 4 + r);
        unsigned long long pr = (((unsigned long long)__float_as_uint(d)) << 32) | rg;
        p = pr < p ? pr : p;
      }
    }
    unsigned long long q = __shfl_xor(p, 16); p = q < p ? q : p;
    q = __shfl_xor(p, 32); p = q < p ? q : p;
    if (quad == 0)
      atomicMin(&colNN[(size_t)b * LL + col0 + wn * 32 + j * 16 + m16], p);
  }
}

// -------- FALLBACK (small ws): fp32 VALU cdist + NN --------
__global__ __launch_bounds__(256) void k_feat_nn(
    const float* __restrict__ zgf, const float* __restrict__ zlf,
    const float* __restrict__ ng, const float* __restrict__ nl,
    unsigned long long* __restrict__ rowNN, unsigned long long* __restrict__ colNN) {
  const int b = blockIdx.z;
  const int row0 = blockIdx.x * 64;
  const int col0 = blockIdx.y * 128;
  const int tid = threadIdx.x;
  const int tx = tid & 15, ty = tid >> 4;
  __shared__ float As[64][20];
  __shared__ float Bs[128][20];
  __shared__ float Ds[64][130];
  const float* Ag = zgf + ((size_t)b * LG + row0) * CH;
  const float* Bg = zlf + ((size_t)b * LL + col0) * CH;
  float acc[4][8];
  #pragma unroll
  for (int i = 0; i < 4; ++i)
    #pragma unroll
    for (int j = 0; j < 8; ++j) acc[i][j] = 0.f;
  const int ar = tid >> 2;
  const int ak = (tid & 3) * 4;
  for (int k0 = 0; k0 < CH; k0 += 16) {
    float4 av  = *(const float4*)(Ag + (size_t)ar * CH + k0 + ak);
    float4 bv0 = *(const float4*)(Bg + (size_t)ar * CH + k0 + ak);
    float4 bv1 = *(const float4*)(Bg + (size_t)(ar + 64) * CH + k0 + ak);
    __syncthreads();
    *(float4*)&As[ar][ak] = av;
    *(float4*)&Bs[ar][ak] = bv0;
    *(float4*)&Bs[ar + 64][ak] = bv1;
    __syncthreads();
    #pragma unroll
    for (int k = 0; k < 16; ++k) {
      float a0 = As[ty][k], a1 = As[ty + 16][k], a2 = As[ty + 32][k], a3 = As[ty + 48][k];
      float bv[8];
      #pragma unroll
      for (int j = 0; j < 8; ++j) bv[j] = Bs[tx + 16 * j][k];
      #pragma unroll
      for (int j = 0; j < 8; ++j) {
        acc[0][j] += a0 * bv[j]; acc[1][j] += a1 * bv[j];
        acc[2][j] += a2 * bv[j]; acc[3][j] += a3 * bv[j];
      }
    }
  }
  float ngr[4], nlc[8];
  #pragma unroll
  for (int i = 0; i < 4; ++i) ngr[i] = ng[b * LG + row0 + ty + 16 * i];
  #pragma unroll
  for (int j = 0; j < 8; ++j) nlc[j] = nl[b * LL + col0 + tx + 16 * j];
  #pragma unroll
  for (int i = 0; i < 4; ++i)
    #pragma unroll
    for (int j = 0; j < 8; ++j)
      Ds[ty + 16 * i][tx + 16 * j] = fmaxf(ngr[i] + nlc[j] - 2.f * acc[i][j], 0.f);
  __syncthreads();
  if (tid < 64) {
    unsigned long long best = ~0ull;
    for (int c = 0; c < 128; ++c) {
      unsigned long long p =
          ((unsigned long long)__float_as_uint(Ds[tid][c]) << 32) | (unsigned)(col0 + c);
      best = p < best ? p : best;
    }
    atomicMin(&rowNN[(size_t)b * LG + row0 + tid], best);
  } else if (tid < 192) {
    int c = tid - 64;
    unsigned long long best = ~0ull;
    for (int r = 0; r < 64; ++r) {
      unsigned long long p =
          ((unsigned long long)__float_as_uint(Ds[r][c]) << 32) | (unsigned)(row0 + r);
      best = p < best ? p : best;
    }
    atomicMin(&colNN[(size_t)b * LL + col0 + c], best);
  }
}

// -------- feature-dir selection + fused final (last block combines) --------
__global__ __launch_bounds__(256) void k_sel(
    const float* __restrict__ zgf, const float* __restrict__ zlf,
    const float* __restrict__ gg, const float* __restrict__ gl,
    const unsigned long long* __restrict__ rowNN,
    const unsigned long long* __restrict__ colNN,
    double* __restrict__ selsum, const double* __restrict__ bsum,
    const float* __restrict__ S, unsigned* __restrict__ done,
    float* __restrict__ out) {
  __shared__ SelSmem sm;
  int b = blockIdx.x;
  if (blockIdx.y == 0)
    sel_case<0>(sm, b, zgf, zlf, gg, gl, rowNN, colNN, selsum);
  else
    sel_case<1>(sm, b, zgf, zlf, gg, gl, rowNN, colNN, selsum);

  // ---- last of 64 blocks performs the final combine ----
  __shared__ unsigned isLast;
  __shared__ float t[2][32];
  __shared__ double sacc[5];
  __shared__ double smf[4];
  __shared__ double totred[2];
  int tid = threadIdx.x, lane = tid & 63, wv = tid >> 6;
  if (tid == 0) {
    __threadfence();
    unsigned old = __hip_atomic_fetch_add(done, 1u, __ATOMIC_ACQ_REL,
                                          __HIP_MEMORY_SCOPE_AGENT);
    isLast = (old == 63u) ? 1u : 0u;
  }
  __syncthreads();
  if (isLast) {
    __threadfence();
    if (tid < 64) {
      int zi = tid >> 5, p = tid & 31;
      float tp = 0.f;
      for (int bb = 0; bb < 32; ++bb) tp += S[zi * 1024 + p * 32 + bb];
      t[zi][p] = tp * (1.f / 32.f);
    } else if (tid < 69) {
      int k = tid - 64;
      double s = 0.0;
      for (int blk = 0; blk < 32; ++blk) s += bsum[blk * 5 + k];
      sacc[k] = s;
    } else if (tid >= 72 && tid < 76) {
      int v = tid - 72;
      double s = 0.0;
      for (int bb = 0; bb < 32; ++bb) s += selsum[v * 32 + bb];
      smf[v] = s;
    }
    __syncthreads();
    if (wv < 2) {
      int zi = wv;
      float u = 0.f;
      for (int bb = 0; bb < 32; ++bb) u += t[zi][bb];
      u *= (1.f / 32.f);
      double s = 0.0;
      for (int e = lane; e < 1024; e += 64) {
        int p = e >> 5, q = e & 31;
        float G = S[zi * 1024 + e] - t[zi][p] - t[zi][q] + u;
        s += (double)G * (double)G;
      }
      for (int off = 32; off; off >>= 1) s += __shfl_down(s, off);
      if (lane == 0) totred[zi] = s;
    }
    __syncthreads();
    if (tid == 0) {
      double inv_g = sacc[0] / (32.0 * 8192.0);
      double v = 0.5 * (sacc[1] + sacc[2]) / 8192.0;
      double c = (totred[0] - sacc[3] + totred[1] - sacc[4]) / (961.0 * 8192.0);
      double gloss = 25.0 * inv_g + 25.0 * v + c;
      double mfg = smf[0] / (32.0 * 20.0 * 512.0);
      double mfl = smf[1] / (32.0 * 4.0 * 512.0);
      double mgg = smf[2] / (32.0 * 20.0 * 512.0);
      double mgl = smf[3] / (32.0 * 4.0 * 512.0);
      double lloss = 25.0 * (0.5 * (mfg + mfl) + 0.5 * (mgg + mgl));
      out[0] = (float)(0.25 * gloss + 0.75 * lloss);
    }
  }
}

extern "C" void kernel_launch(void* const* d_in, const int* in_sizes, int n_in,
                              void* d_out, int out_size, void* d_ws, size_t ws_size,
                              hipStream_t stream) {
  const float* zg  = (const float*)d_in[0];
  const float* zl  = (const float*)d_in[1];
  const float* zgf = (const float*)d_in[2];
  const float* zlf = (const float*)d_in[3];
  const float* gg  = (const float*)d_in[4];
  const float* glo = (const float*)d_in[5];

  char* ws = (char*)d_ws;
  float* S       = (float*)(ws + OFF_S);
  double* bsum   = (double*)(ws + OFF_BSUM);
  double* selsum = (double*)(ws + OFF_SELSUM);
  unsigned* done = (unsigned*)(ws + OFF_DONE);
  float* ng = (float*)(ws + OFF_NG);
  float* nl = (float*)(ws + OFF_NL);
  unsigned long long* rowNN = (unsigned long long*)(ws + OFF_ROWNN);
  unsigned long long* colNN = (unsigned long long*)(ws + OFF_COLNN);
  unsigned short* Abf = (unsigned short*)(ws + OFF_ABF);
  unsigned short* Bbf = (unsigned short*)(ws + OFF_BBF);

  int do_bf16 = (ws_size >= WS_NEED) ? 1 : 0;

  k_front<<<7808, 256, 0, stream>>>(zg, zl, zgf, zlf, gg, glo, bsum, S,
                                    Abf, Bbf, ng, nl, rowNN, selsum, done, do_bf16);
  if (do_bf16) {
    k_feat_mfma<<<dim3(LG / 64, LL / 64, BATCH), 256, 0, stream>>>(
        Abf, Bbf, ng, nl, rowNN, colNN);
  } else {
    k_feat_nn<<<dim3(LG / 64, LL / 128, BATCH), 256, 0, stream>>>(
        zgf, zlf, ng, nl, rowNN, colNN);
  }
  k_sel<<<dim3(BATCH, 2), 256, 0, stream>>>(zgf, zlf, gg, glo, rowNN, colNN,
                                            selsum, bsum, S, done, (float*)d_out);
}